// Round 7
// baseline (201.159 us; speedup 1.0000x reference)
//
#include <hip/hip_runtime.h>
#include <hip/hip_bf16.h>
#include <math.h>

#define N_NODES 4096
#define DIN     512
#define DOUT    256
#define NH      3
#define BN_EPS  1e-5f
#define NPH     (N_NODES * DOUT)

typedef __attribute__((ext_vector_type(8))) short short8;
typedef __attribute__((ext_vector_type(4))) float f32x4;

// float -> bf16 bits (RNE) and back
__device__ __forceinline__ short f2bf(float x) {
    union { float f; unsigned u; } v; v.f = x;
    unsigned r = (v.u + 0x7FFFu + ((v.u >> 16) & 1u)) >> 16;
    return (short)r;
}
__device__ __forceinline__ float bf2f(short b) {
    union { float f; unsigned u; } v; v.u = ((unsigned)(unsigned short)b) << 16;
    return v.f;
}

// ---------------------------------------------------------------------------
// K1f: F [4096][512] f32 -> Fhi/Flo bf16 (row-major), split once.
// ---------------------------------------------------------------------------
__global__ __launch_bounds__(256) void k1f_split(const float* __restrict__ F,
                                                 short* __restrict__ Fhi,
                                                 short* __restrict__ Flo) {
    const size_t base = ((size_t)blockIdx.x * 256 + threadIdx.x) * 8;
    float4 v0 = *(const float4*)(F + base);
    float4 v1 = *(const float4*)(F + base + 4);
    float xs[8] = {v0.x, v0.y, v0.z, v0.w, v1.x, v1.y, v1.z, v1.w};
    short hi[8], lo[8];
    #pragma unroll
    for (int j = 0; j < 8; ++j) {
        short hb = f2bf(xs[j]);
        hi[j] = hb;
        lo[j] = f2bf(xs[j] - bf2f(hb));
    }
    *(short8*)(Fhi + base) = *(short8*)hi;
    *(short8*)(Flo + base) = *(short8*)lo;
}

// ---------------------------------------------------------------------------
// K1w: W [3][512][256] f32 -> W^T hi/lo bf16 [3][256][512]
// ---------------------------------------------------------------------------
__global__ __launch_bounds__(256) void k1w_split(const float* __restrict__ W,
                                                 short* __restrict__ WhiT,
                                                 short* __restrict__ WloT) {
    __shared__ float tile[64][72];
    const int h  = blockIdx.z;
    const int k0 = blockIdx.y * 64;
    const int n0 = blockIdx.x * 64;
    const int t  = threadIdx.x;
    {
        const int col4 = (t & 15) * 4;
        #pragma unroll
        for (int p = 0; p < 4; ++p) {
            const int row = p * 16 + (t >> 4);
            float4 v = *(const float4*)(W + (size_t)h * DIN * DOUT + (size_t)(k0 + row) * DOUT + n0 + col4);
            *(float4*)&tile[row][col4] = v;
        }
    }
    __syncthreads();
    const int n  = t >> 2;
    const int kc = (t & 3) * 16;
    short hi[16], lo[16];
    #pragma unroll
    for (int i = 0; i < 16; ++i) {
        float x = tile[kc + i][n];
        short hb = f2bf(x);
        hi[i] = hb;
        lo[i] = f2bf(x - bf2f(hb));
    }
    short* oh = WhiT + ((size_t)h * DOUT + n0 + n) * DIN + k0 + kc;
    short* ol = WloT + ((size_t)h * DOUT + n0 + n) * DIN + k0 + kc;
    *(short8*)(oh)     = *(short8*)&hi[0];
    *(short8*)(oh + 8) = *(short8*)&hi[8];
    *(short8*)(ol)     = *(short8*)&lo[0];
    *(short8*)(ol + 8) = *(short8*)&lo[8];
}

// ---------------------------------------------------------------------------
// K1: proj[h] = F @ W[h] via bf16x3 split MFMA. Tile 64(M)x64(N), BK=32,
// 4 waves each 32x32 (2x2 16x16 frags). Grid 768 blocks = 3/CU = 12 waves/CU
// (was 1.5 blocks/CU at 128x64 -> latency-exposed).
// LDS rows padded to 40 shorts (80 B): frag b128 reads cycle banks period 8
// -> 2-way aliasing (free per m136).
// MFMA 16x16x32_bf16: A row=lane&15, k=8*(lane>>4)+j; B col=lane&15;
// D col=lane&15, row=4*(lane>>4)+reg.
// ---------------------------------------------------------------------------
#define APAD 40

__global__ __launch_bounds__(256) void k1_proj(const short* __restrict__ Fhi,
                                               const short* __restrict__ Flo,
                                               const short* __restrict__ WhiT,
                                               const short* __restrict__ WloT,
                                               float* __restrict__ proj) {
    __shared__ short Ahi[64][APAD], Alo[64][APAD];
    __shared__ short Bhi[64][APAD], Blo[64][APAD];

    const int h    = blockIdx.z;
    const int mblk = blockIdx.y;
    const int nblk = blockIdx.x;
    const int t    = threadIdx.x;
    const int wid  = t >> 6;
    const int l    = t & 63;
    const int wm   = wid >> 1;          // 0..1 (32-row half)
    const int wn   = wid & 1;           // 0..1 (32-col half)
    const int lr   = l & 15;
    const int lk8  = (l >> 4) * 8;

    const int srow = t >> 2;            // 0..63
    const int skc  = (t & 3) * 8;       // 0..24

    const short* FhB = Fhi + (size_t)(mblk * 64 + srow) * DIN + skc;
    const short* FlB = Flo + (size_t)(mblk * 64 + srow) * DIN + skc;
    const short* WhB = WhiT + ((size_t)h * DOUT + nblk * 64 + srow) * DIN + skc;
    const short* WlB = WloT + ((size_t)h * DOUT + nblk * 64 + srow) * DIN + skc;

    f32x4 acc[2][2];
    #pragma unroll
    for (int mf = 0; mf < 2; ++mf)
        #pragma unroll
        for (int nf = 0; nf < 2; ++nf)
            acc[mf][nf] = (f32x4){0.f, 0.f, 0.f, 0.f};

    for (int kb = 0; kb < DIN; kb += 32) {
        *(short8*)&Ahi[srow][skc] = *(const short8*)(FhB + kb);
        *(short8*)&Alo[srow][skc] = *(const short8*)(FlB + kb);
        *(short8*)&Bhi[srow][skc] = *(const short8*)(WhB + kb);
        *(short8*)&Blo[srow][skc] = *(const short8*)(WlB + kb);
        __syncthreads();

        short8 ah[2], al[2], bh[2], bl[2];
        #pragma unroll
        for (int mf = 0; mf < 2; ++mf) {
            ah[mf] = *(const short8*)&Ahi[wm * 32 + mf * 16 + lr][lk8];
            al[mf] = *(const short8*)&Alo[wm * 32 + mf * 16 + lr][lk8];
        }
        #pragma unroll
        for (int nf = 0; nf < 2; ++nf) {
            bh[nf] = *(const short8*)&Bhi[wn * 32 + nf * 16 + lr][lk8];
            bl[nf] = *(const short8*)&Blo[wn * 32 + nf * 16 + lr][lk8];
        }
        #pragma unroll
        for (int mf = 0; mf < 2; ++mf)
            #pragma unroll
            for (int nf = 0; nf < 2; ++nf) {
                acc[mf][nf] = __builtin_amdgcn_mfma_f32_16x16x32_bf16(ah[mf], bh[nf], acc[mf][nf], 0, 0, 0);
                acc[mf][nf] = __builtin_amdgcn_mfma_f32_16x16x32_bf16(ah[mf], bl[nf], acc[mf][nf], 0, 0, 0);
                acc[mf][nf] = __builtin_amdgcn_mfma_f32_16x16x32_bf16(al[mf], bh[nf], acc[mf][nf], 0, 0, 0);
            }
        __syncthreads();
    }

    float* P = proj + (size_t)h * NPH
             + (size_t)(mblk * 64 + wm * 32) * DOUT + nblk * 64 + wn * 32;
    #pragma unroll
    for (int mf = 0; mf < 2; ++mf)
        #pragma unroll
        for (int nf = 0; nf < 2; ++nf)
            #pragma unroll
            for (int r = 0; r < 4; ++r)
                P[(size_t)(mf * 16 + (l >> 4) * 4 + r) * DOUT + nf * 16 + lr] = acc[mf][nf][r];
}

// ---------------------------------------------------------------------------
// K2: s_src[h][n] = proj[h][n][:] . score_src[h][:], same for s_tgt
// ---------------------------------------------------------------------------
__global__ __launch_bounds__(256) void k2_scores(const float* __restrict__ proj,
                                                 const float* __restrict__ ssw,
                                                 const float* __restrict__ stw,
                                                 float* __restrict__ s_src,
                                                 float* __restrict__ s_tgt) {
    const int wave = threadIdx.x >> 6;
    const int lane = threadIdx.x & 63;
    const int row  = blockIdx.x * 4 + wave;      // = h*4096+n
    const int h    = row >> 12;

    const float* p = proj + (size_t)row * DOUT;
    float4 pv = *(const float4*)(p + lane * 4);
    float4 a  = *(const float4*)(ssw + h * DOUT + lane * 4);
    float4 b  = *(const float4*)(stw + h * DOUT + lane * 4);
    float ds = pv.x * a.x + pv.y * a.y + pv.z * a.z + pv.w * a.w;
    float dt = pv.x * b.x + pv.y * b.y + pv.z * b.z + pv.w * b.w;
    #pragma unroll
    for (int off = 32; off; off >>= 1) {
        ds += __shfl_down(ds, off);
        dt += __shfl_down(dt, off);
    }
    if (lane == 0) { s_src[row] = ds; s_tgt[row] = dt; }
}

// ---------------------------------------------------------------------------
// K3: 512 threads (8 waves) per block, 4 rows; TWO waves per row, each owning
// one 2048-col half. float4 adj loads (1KB/wave-instr; compaction order is
// irrelevant since softmax/gather are order-agnostic). Pair-softmax computed
// redundantly in-wave (no exchange). Gather split by half across the wave
// pair; LDS partial-combine. 8192 waves total = 32/CU (100% occ ceiling).
// ---------------------------------------------------------------------------
#define SEGC 64

__global__ __launch_bounds__(512) void k3_attn(const float* __restrict__ adj,
                                               const float* __restrict__ proj,
                                               const float* __restrict__ s_src,
                                               const float* __restrict__ s_tgt,
                                               const float* __restrict__ bias,
                                               float* __restrict__ outp) {
    __shared__ int   ej[4][2 * SEGC];
    __shared__ float ea[4][2 * SEGC];
    __shared__ float ep[4][2 * SEGC][NH];
    __shared__ int   cnts[4][2];
    __shared__ float part[4][NH][DOUT];

    const int r0   = blockIdx.x * 4;
    const int t    = threadIdx.x;
    const int w    = t >> 6;            // 0..7
    const int lane = t & 63;
    const int r    = w >> 1;            // row slot 0..3
    const int hs   = w & 1;             // half 0..1
    const int row  = r0 + r;
    const unsigned long long ltmask = (1ull << lane) - 1ull;

    // ---- phase A: compact nonzeros of cols [hs*2048, +2048) ----
    const float* arow = adj + (size_t)row * N_NODES + hs * 2048;
    int cnt = 0;
    #pragma unroll
    for (int it = 0; it < 8; ++it) {
        float4 v = *(const float4*)(arow + it * 256 + lane * 4);
        float av[4] = {v.x, v.y, v.z, v.w};
        #pragma unroll
        for (int k = 0; k < 4; ++k) {
            unsigned long long m = __ballot(av[k] != 0.0f);
            if (av[k] != 0.0f) {
                int pos = cnt + (int)__popcll(m & ltmask);
                if (pos < SEGC) {
                    ej[r][hs * SEGC + pos] = hs * 2048 + it * 256 + lane * 4 + k;
                    ea[r][hs * SEGC + pos] = av[k];
                }
            }
            cnt += (int)__popcll(m);
        }
    }
    if (lane == 0) cnts[r][hs] = (cnt > SEGC ? SEGC : cnt);
    __syncthreads();

    // ---- phase B: softmax (each wave of the pair computes redundantly) ----
    const int n0 = cnts[r][0], n1 = cnts[r][1];
    const int j0 = (lane < n0) ? ej[r][lane] : 0;
    const int j1 = (lane < n1) ? ej[r][SEGC + lane] : 0;
    const float aa0 = (lane < n0) ? ea[r][lane] : 0.f;
    const float aa1 = (lane < n1) ? ea[r][SEGC + lane] : 0.f;
    const int myn = hs ? n1 : n0;

    float inv[NH];
    #pragma unroll
    for (int h = 0; h < NH; ++h) {
        const float  ss = s_src[h * N_NODES + row];
        const float* st = s_tgt + h * N_NODES;
        float lg0 = -1e30f, lg1 = -1e30f;
        if (lane < n0) { float x = ss + st[j0]; lg0 = (x > 0.f ? x : 0.2f * x) + aa0; }
        if (lane < n1) { float x = ss + st[j1]; lg1 = (x > 0.f ? x : 0.2f * x) + aa1; }
        float mx = fmaxf(lg0, lg1);
        #pragma unroll
        for (int off = 32; off; off >>= 1) mx = fmaxf(mx, __shfl_xor(mx, off));
        float p0 = __expf(lg0 - mx), p1 = __expf(lg1 - mx);
        float sum = p0 + p1;
        #pragma unroll
        for (int off = 32; off; off >>= 1) sum += __shfl_xor(sum, off);
        inv[h] = 1.0f / sum;
        // store own half's p (wave reads back its own writes; no barrier)
        if (lane < myn) ep[r][hs * SEGC + lane][h] = hs ? p1 : p0;
    }

    // ---- phase C: gather own half's edges; lane owns dims 4l..4l+3 ----
    const int d0 = lane * 4;
    const int base = hs * SEGC;
    float4 a0 = make_float4(0.f, 0.f, 0.f, 0.f);
    float4 a1 = a0, a2 = a0;
    #pragma unroll 4
    for (int e = 0; e < myn; ++e) {
        const int   j  = ej[r][base + e];
        const float p0 = ep[r][base + e][0];
        const float p1 = ep[r][base + e][1];
        const float p2 = ep[r][base + e][2];
        const float* pb = proj + (size_t)j * DOUT + d0;
        float4 v0 = *(const float4*)pb;
        float4 v1 = *(const float4*)(pb + NPH);
        float4 v2 = *(const float4*)(pb + 2 * NPH);
        a0.x = fmaf(p0, v0.x, a0.x); a0.y = fmaf(p0, v0.y, a0.y);
        a0.z = fmaf(p0, v0.z, a0.z); a0.w = fmaf(p0, v0.w, a0.w);
        a1.x = fmaf(p1, v1.x, a1.x); a1.y = fmaf(p1, v1.y, a1.y);
        a1.z = fmaf(p1, v1.z, a1.z); a1.w = fmaf(p1, v1.w, a1.w);
        a2.x = fmaf(p2, v2.x, a2.x); a2.y = fmaf(p2, v2.y, a2.y);
        a2.z = fmaf(p2, v2.z, a2.z); a2.w = fmaf(p2, v2.w, a2.w);
    }

    if (hs == 1) {
        *(float4*)&part[r][0][d0] = a0;
        *(float4*)&part[r][1][d0] = a1;
        *(float4*)&part[r][2][d0] = a2;
    }
    __syncthreads();
    if (hs == 0) {
        float4 b0 = *(float4*)&part[r][0][d0];
        float4 b1 = *(float4*)&part[r][1][d0];
        float4 b2 = *(float4*)&part[r][2][d0];
        const float s3 = 1.0f / (float)NH;
        const float4 bv = *(const float4*)(bias + d0);
        float4 o;
        o.x = ((a0.x + b0.x) * inv[0] + (a1.x + b1.x) * inv[1] + (a2.x + b2.x) * inv[2]) * s3 + bv.x;
        o.y = ((a0.y + b0.y) * inv[0] + (a1.y + b1.y) * inv[1] + (a2.y + b2.y) * inv[2]) * s3 + bv.y;
        o.z = ((a0.z + b0.z) * inv[0] + (a1.z + b1.z) * inv[1] + (a2.z + b2.z) * inv[2]) * s3 + bv.z;
        o.w = ((a0.w + b0.w) * inv[0] + (a1.w + b1.w) * inv[1] + (a2.w + b2.w) * inv[2]) * s3 + bv.w;
        *(float4*)(outp + (size_t)row * DOUT + d0) = o;
    }
}

// ---------------------------------------------------------------------------
// K4: BN column stats — partial sums per 64-row slab, atomicAdd into sums[512]
// ---------------------------------------------------------------------------
__global__ __launch_bounds__(256) void k4_stats(const float* __restrict__ outp,
                                                float* __restrict__ sums) {
    const int t  = threadIdx.x;
    const int r0 = blockIdx.x * 64;
    float s = 0.f, s2 = 0.f;
    for (int r = 0; r < 64; ++r) {
        float v = outp[(size_t)(r0 + r) * DOUT + t];
        s  += v;
        s2 += v * v;
    }
    atomicAdd(&sums[t], s);
    atomicAdd(&sums[DOUT + t], s2);
}

// ---------------------------------------------------------------------------
// K5: BN normalize (batch stats, biased var) + ReLU, in place
// ---------------------------------------------------------------------------
__global__ __launch_bounds__(256) void k5_bn(float* __restrict__ outp,
                                             const float* __restrict__ sums,
                                             const float* __restrict__ gamma,
                                             const float* __restrict__ beta) {
    const int idx = blockIdx.x * 256 + threadIdx.x;
    float4 v = *(float4*)(outp + (size_t)idx * 4);
    const int c0 = (idx * 4) & (DOUT - 1);
    float vv[4] = {v.x, v.y, v.z, v.w};
    #pragma unroll
    for (int j = 0; j < 4; ++j) {
        const int c = c0 + j;
        float mu  = sums[c] * (1.0f / N_NODES);
        float var = sums[DOUT + c] * (1.0f / N_NODES) - mu * mu;
        float sc  = gamma[c] * rsqrtf(var + BN_EPS);
        float sh  = beta[c] - mu * sc;
        vv[j] = fmaxf(0.f, fmaf(vv[j], sc, sh));
    }
    *(float4*)(outp + (size_t)idx * 4) = make_float4(vv[0], vv[1], vv[2], vv[3]);
}

// ---------------------------------------------------------------------------
extern "C" void kernel_launch(void* const* d_in, const int* in_sizes, int n_in,
                              void* d_out, int out_size, void* d_ws, size_t ws_size,
                              hipStream_t stream) {
    const float* F     = (const float*)d_in[0];   // [4096,512]
    const float* A     = (const float*)d_in[1];   // [4096,4096]
    const float* W     = (const float*)d_in[2];   // [3,512,256]
    const float* bias  = (const float*)d_in[3];   // [256]
    const float* ssw   = (const float*)d_in[4];   // [3,256,1]
    const float* stw   = (const float*)d_in[5];   // [3,256,1]
    const float* gamma = (const float*)d_in[6];   // [256]
    const float* beta  = (const float*)d_in[7];   // [256]
    float* out = (float*)d_out;                   // [4096,256]

    float* proj  = (float*)d_ws;                          // 12.58 MB
    float* s_src = proj  + (size_t)NH * N_NODES * DOUT;   // 3*4096
    float* s_tgt = s_src + NH * N_NODES;                  // 3*4096
    float* sums  = s_tgt + NH * N_NODES;                  // 512
    short* WhiT  = (short*)(sums + 2 * DOUT);             // 0.75 MB
    short* WloT  = WhiT + (size_t)NH * DOUT * DIN;        // 0.75 MB
    short* Fhi   = WloT + (size_t)NH * DOUT * DIN;        // 4 MB
    short* Flo   = Fhi  + (size_t)N_NODES * DIN;          // 4 MB

    hipMemsetAsync(sums, 0, 2 * DOUT * sizeof(float), stream);
    k1f_split<<<(size_t)N_NODES * DIN / 8 / 256, 256, 0, stream>>>(F, Fhi, Flo);
    k1w_split<<<dim3(DOUT / 64, DIN / 64, NH), 256, 0, stream>>>(W, WhiT, WloT);
    k1_proj<<<dim3(DOUT / 64, N_NODES / 64, NH), 256, 0, stream>>>(Fhi, Flo, WhiT, WloT, proj);
    k2_scores<<<NH * N_NODES / 4, 256, 0, stream>>>(proj, ssw, stw, s_src, s_tgt);
    k3_attn<<<N_NODES / 4, 512, 0, stream>>>(A, proj, s_src, s_tgt, bias, out);
    k4_stats<<<N_NODES / 64, 256, 0, stream>>>(out, sums);
    k5_bn<<<(size_t)N_NODES * DOUT / 4 / 256, 256, 0, stream>>>(out, sums, gamma, beta);
}